// Round 3
// baseline (226660.352 us; speedup 1.0000x reference)
//
#include <hip/hip_runtime.h>

#define NROWS 65536
#define DD 256
#define KK 1024
#define NCB 8
#define QN 16777216
#define IDXN 524288

// Defeat -ffp-contract=fast: force the product to materialize as a rounded
// fp32 value so the following add cannot be fused into an FMA.
__device__ __forceinline__ float fp32_barrier(float x) {
    asm volatile("" : "+v"(x));
    return x;
}

// ---- numpy pairwise ||w||^2 per codeword (bitwise np.sum semantics) ----
__global__ void wss_kernel(const float* __restrict__ cb, float* __restrict__ wss) {
    const int g = blockIdx.x * blockDim.x + threadIdx.x;
    if (g >= NCB * KK) return;
    const float* w = cb + (size_t)g * DD;
    float res0 = 0.f, res1 = 0.f;
    #pragma unroll
    for (int half = 0; half < 2; ++half) {
        const float* p = w + half * 128;
        float acc[8];
        #pragma unroll
        for (int j = 0; j < 8; ++j) acc[j] = fp32_barrier(p[j] * p[j]);
        #pragma unroll
        for (int i = 8; i < 128; i += 8)
            #pragma unroll
            for (int j = 0; j < 8; ++j) acc[j] += fp32_barrier(p[i + j] * p[i + j]);
        const float t = ((acc[0] + acc[1]) + (acc[2] + acc[3])) +
                        ((acc[4] + acc[5]) + (acc[6] + acc[7]));
        if (half == 0) res0 = t; else res1 = t;
    }
    wss[g] = res0 + res1;
}

// ---- one RVQ step: fp32 trajectory + np-bitwise fp32 scores + argmin ----
__launch_bounds__(64, 1)
__global__ void step_kernel(const float* __restrict__ z, const float* __restrict__ cb,
                            float* __restrict__ out_idx, const float* __restrict__ wss,
                            double* __restrict__ loss, int c)
{
    const int lane = threadIdx.x;          // blockDim = 64, one wave
    const int n = blockIdx.x * 64 + lane;  // one row per lane

    // ---- residual in fp32, exact reference trajectory (elementwise subs) ----
    float r[256];
    {
        const float* zr = z + (size_t)n * DD;
        #pragma unroll
        for (int q = 0; q < 64; ++q) {
            const float4 v = *(const float4*)(zr + q * 4);
            r[q * 4 + 0] = v.x; r[q * 4 + 1] = v.y;
            r[q * 4 + 2] = v.z; r[q * 4 + 3] = v.w;
        }
    }
    for (int h = 0; h < c; ++h) {
        const int ih = (int)out_idx[(size_t)n * NCB + h];
        const float* w = cb + ((size_t)h * KK + ih) * DD;
        #pragma unroll
        for (int q = 0; q < 64; ++q) {
            const float4 v = *(const float4*)(w + q * 4);
            r[q * 4 + 0] -= v.x; r[q * 4 + 1] -= v.y;
            r[q * 4 + 2] -= v.z; r[q * 4 + 3] -= v.w;
        }
    }

    // ---- loss term c-1: fp64 sum of squares of the fp32 residual values ----
    {
        double ssq = 0.0;
        #pragma unroll
        for (int d = 0; d < 256; ++d) { const double v = (double)r[d]; ssq += v * v; }
        for (int off = 32; off; off >>= 1) ssq += __shfl_down(ssq, off);
        if (lane == 0 && c > 0) atomicAdd(&loss[c - 1], ssq);
    }

    // ---- rss: numpy pairwise fp32 sum of fl(r_d^2), n=256 = pw128 + pw128 ----
    float rss;
    {
        float acc[8];
        #pragma unroll
        for (int j = 0; j < 8; ++j) acc[j] = fp32_barrier(r[j] * r[j]);
        #pragma unroll
        for (int i = 8; i < 128; i += 8)
            #pragma unroll
            for (int j = 0; j < 8; ++j) acc[j] += fp32_barrier(r[i + j] * r[i + j]);
        const float h1 = ((acc[0] + acc[1]) + (acc[2] + acc[3])) +
                         ((acc[4] + acc[5]) + (acc[6] + acc[7]));
        #pragma unroll
        for (int j = 0; j < 8; ++j) acc[j] = fp32_barrier(r[128 + j] * r[128 + j]);
        #pragma unroll
        for (int i = 8; i < 128; i += 8)
            #pragma unroll
            for (int j = 0; j < 8; ++j) acc[j] += fp32_barrier(r[128 + i + j] * r[128 + i + j]);
        const float h2 = ((acc[0] + acc[1]) + (acc[2] + acc[3])) +
                         ((acc[4] + acc[5]) + (acc[6] + acc[7]));
        rss = h1 + h2;
    }

    // ---- scores for all k: ab = sequential-d fp32 FMA chain (sgemm order),
    //      score = fl(fl(rss - 2*ab) + wss);  argmin with first-min ties ----
    unsigned long long best = 0xFFFFFFFFFFFFFFFFULL;
    const float* wc = cb + (size_t)c * KK * DD;
    const float* wssc = wss + c * KK;

    for (int kg = 0; kg < KK / 4; ++kg) {
        const int k0 = kg * 4;
        const float* w0p = wc + (size_t)(k0 + 0) * DD;
        const float* w1p = wc + (size_t)(k0 + 1) * DD;
        const float* w2p = wc + (size_t)(k0 + 2) * DD;
        const float* w3p = wc + (size_t)(k0 + 3) * DD;
        float a0 = 0.f, a1 = 0.f, a2 = 0.f, a3 = 0.f;
        #pragma unroll
        for (int q = 0; q < 64; ++q) {
            const float4 w0 = *(const float4*)(w0p + q * 4);
            const float4 w1 = *(const float4*)(w1p + q * 4);
            const float4 w2 = *(const float4*)(w2p + q * 4);
            const float4 w3 = *(const float4*)(w3p + q * 4);
            const float r0 = r[q * 4 + 0], r1 = r[q * 4 + 1];
            const float r2 = r[q * 4 + 2], r3 = r[q * 4 + 3];
            a0 = __builtin_fmaf(r0, w0.x, a0);
            a1 = __builtin_fmaf(r0, w1.x, a1);
            a2 = __builtin_fmaf(r0, w2.x, a2);
            a3 = __builtin_fmaf(r0, w3.x, a3);
            a0 = __builtin_fmaf(r1, w0.y, a0);
            a1 = __builtin_fmaf(r1, w1.y, a1);
            a2 = __builtin_fmaf(r1, w2.y, a2);
            a3 = __builtin_fmaf(r1, w3.y, a3);
            a0 = __builtin_fmaf(r2, w0.z, a0);
            a1 = __builtin_fmaf(r2, w1.z, a1);
            a2 = __builtin_fmaf(r2, w2.z, a2);
            a3 = __builtin_fmaf(r2, w3.z, a3);
            a0 = __builtin_fmaf(r3, w0.w, a0);
            a1 = __builtin_fmaf(r3, w1.w, a1);
            a2 = __builtin_fmaf(r3, w2.w, a2);
            a3 = __builtin_fmaf(r3, w3.w, a3);
        }
        #pragma unroll
        for (int j = 0; j < 4; ++j) {
            const float aj = (j == 0) ? a0 : (j == 1) ? a1 : (j == 2) ? a2 : a3;
            const float sc = (rss - 2.0f * aj) + wssc[k0 + j];
            unsigned u = __float_as_uint(sc);
            u = ((int)u < 0) ? ~u : (u | 0x80000000u);
            const unsigned long long e = ((unsigned long long)u << 32) | (unsigned)(k0 + j);
            if (e < best) best = e;
        }
    }

    out_idx[(size_t)n * NCB + c] = (float)(int)(best & 0xFFFFFFFFULL);
}

// ---- quantized (fp32 sequential accumulation, reference order) + last loss ----
__global__ void final_kernel(const float* __restrict__ z, const float* __restrict__ cb,
                             const float* __restrict__ out_idx, float* __restrict__ outq,
                             double* __restrict__ loss)
{
    const int lane = threadIdx.x & 63;
    const int wid = (blockIdx.x * blockDim.x + threadIdx.x) >> 6;
    if (wid >= NROWS) return;
    const int n = wid, d = lane * 4;
    float4 rv = *(const float4*)(z + (size_t)n * DD + d);
    float q0 = 0.f, q1 = 0.f, q2 = 0.f, q3 = 0.f;
    for (int j = 0; j < NCB; ++j) {
        const int hidx = (int)out_idx[(size_t)n * NCB + j];
        const float4 wv = *(const float4*)(cb + ((size_t)j * KK + hidx) * DD + d);
        q0 += wv.x; q1 += wv.y; q2 += wv.z; q3 += wv.w;
        rv.x -= wv.x; rv.y -= wv.y; rv.z -= wv.z; rv.w -= wv.w;
    }
    *(float4*)(outq + (size_t)n * DD + d) = make_float4(q0, q1, q2, q3);
    double ss = (double)rv.x * rv.x + (double)rv.y * rv.y +
                (double)rv.z * rv.z + (double)rv.w * rv.w;
    for (int off = 32; off; off >>= 1) ss += __shfl_down(ss, off);
    if (lane == 0) atomicAdd(&loss[NCB - 1], ss);
}

__global__ void loss_write_kernel(const double* __restrict__ loss, float* __restrict__ out_loss) {
    double s = 0.0;
    for (int i = 0; i < NCB; ++i) s += loss[i];
    *out_loss = (float)(s / 16777216.0);
}

extern "C" void kernel_launch(void* const* d_in, const int* in_sizes, int n_in,
                              void* d_out, int out_size, void* d_ws, size_t ws_size,
                              hipStream_t stream)
{
    const float* z  = (const float*)d_in[0];
    const float* cb = (const float*)d_in[1];
    float* outq     = (float*)d_out;
    float* out_idx  = outq + QN;
    float* out_loss = outq + QN + IDXN;

    double* loss = (double*)d_ws;                 // 64 B
    float*  wss  = (float*)((char*)d_ws + 64);    // 32 KB

    hipMemsetAsync(d_ws, 0, 64, stream);
    wss_kernel<<<dim3((NCB * KK + 255) / 256), dim3(256), 0, stream>>>(cb, wss);
    for (int c = 0; c < NCB; ++c) {
        step_kernel<<<dim3(NROWS / 64), dim3(64), 0, stream>>>(z, cb, out_idx, wss, loss, c);
    }
    final_kernel<<<dim3(NROWS / 4), dim3(256), 0, stream>>>(z, cb, out_idx, outq, loss);
    loss_write_kernel<<<1, 1, 0, stream>>>(loss, out_loss);
}

// Round 4
// 15941.737 us; speedup vs baseline: 14.2180x; 14.2180x over previous
//
#include <hip/hip_runtime.h>

#define NROWS 65536
#define DD 256
#define KK 1024
#define NCB 8
#define QN 16777216
#define IDXN 524288

// Defeat -ffp-contract=fast: force the product to materialize as a rounded
// fp32 value so the following add cannot be fused into an FMA.
__device__ __forceinline__ float fp32_barrier(float x) {
    asm volatile("" : "+v"(x));
    return x;
}

// ---- numpy pairwise ||w||^2 per codeword (bitwise np.sum semantics) ----
__global__ void wss_kernel(const float* __restrict__ cb, float* __restrict__ wss) {
    const int g = blockIdx.x * blockDim.x + threadIdx.x;
    if (g >= NCB * KK) return;
    const float* w = cb + (size_t)g * DD;
    float res0 = 0.f, res1 = 0.f;
    #pragma unroll
    for (int half = 0; half < 2; ++half) {
        const float* p = w + half * 128;
        float acc[8];
        #pragma unroll
        for (int j = 0; j < 8; ++j) acc[j] = fp32_barrier(p[j] * p[j]);
        #pragma unroll
        for (int i = 8; i < 128; i += 8)
            #pragma unroll
            for (int j = 0; j < 8; ++j) acc[j] += fp32_barrier(p[i + j] * p[i + j]);
        const float t = ((acc[0] + acc[1]) + (acc[2] + acc[3])) +
                        ((acc[4] + acc[5]) + (acc[6] + acc[7]));
        if (half == 0) res0 = t; else res1 = t;
    }
    wss[g] = res0 + res1;
}

// ---- one RVQ step, tiled: 64 rows/block (LDS-staged), 8 waves x 128 k ----
// Bitwise-identical arithmetic to the R3 per-lane version: each (row,k)
// accumulator is a single fp32 fma chain over d=0..255 ascending; score
// = (rss - 2*a) + wss with numpy-pairwise rss/wss; first-min argmin.
__launch_bounds__(512, 4)
__global__ void step_kernel(const float* __restrict__ z, const float* __restrict__ cb,
                            float* __restrict__ out_idx, const float* __restrict__ wss,
                            double* __restrict__ loss, int c)
{
    __shared__ float r_s[DD][65];                 // transposed, 65: 2-way aliasing only
    __shared__ float rss_s[64];
    __shared__ unsigned long long arena[8][64];
    __shared__ double lred[8];

    const int tid = threadIdx.x;
    const int lane = tid & 63;
    const int wv = tid >> 6;
    const int row0 = blockIdx.x * 64;

    // ---- stage residual tile: fp32 reference trajectory (elementwise subs) ----
    {
        const int row = tid >> 3;           // 0..63
        const int d0 = (tid & 7) * 32;      // 8 chunks of 32 d
        const int n = row0 + row;
        float rr[32];
        const float* zr = z + (size_t)n * DD + d0;
        #pragma unroll
        for (int q = 0; q < 8; ++q) {
            const float4 v = *(const float4*)(zr + q * 4);
            rr[q * 4 + 0] = v.x; rr[q * 4 + 1] = v.y;
            rr[q * 4 + 2] = v.z; rr[q * 4 + 3] = v.w;
        }
        for (int h = 0; h < c; ++h) {
            const int ih = (int)out_idx[(size_t)n * NCB + h];
            const float* w = cb + ((size_t)h * KK + ih) * DD + d0;
            #pragma unroll
            for (int q = 0; q < 8; ++q) {
                const float4 v = *(const float4*)(w + q * 4);
                rr[q * 4 + 0] -= v.x; rr[q * 4 + 1] -= v.y;
                rr[q * 4 + 2] -= v.z; rr[q * 4 + 3] -= v.w;
            }
        }
        double ssq = 0.0;
        #pragma unroll
        for (int j = 0; j < 32; ++j) {
            r_s[d0 + j][row] = rr[j];
            const double v = (double)rr[j];
            ssq += v * v;
        }
        if (c > 0) {
            for (int off = 32; off; off >>= 1) ssq += __shfl_down(ssq, off);
            if (lane == 0) lred[wv] = ssq;
        }
    }
    __syncthreads();
    if (c > 0 && tid == 0) {
        double s = 0.0;
        #pragma unroll
        for (int w = 0; w < 8; ++w) s += lred[w];
        atomicAdd(&loss[c - 1], s);
    }

    // ---- rss: numpy pairwise (pw128 + pw128) over staged fp32 residual ----
    if (tid < 64) {
        float res[2];
        #pragma unroll
        for (int half = 0; half < 2; ++half) {
            const int base = half * 128;
            float acc[8];
            #pragma unroll
            for (int j = 0; j < 8; ++j) {
                const float x = r_s[base + j][tid];
                acc[j] = fp32_barrier(x * x);
            }
            #pragma unroll
            for (int i = 8; i < 128; i += 8)
                #pragma unroll
                for (int j = 0; j < 8; ++j) {
                    const float x = r_s[base + i + j][tid];
                    acc[j] += fp32_barrier(x * x);
                }
            res[half] = ((acc[0] + acc[1]) + (acc[2] + acc[3])) +
                        ((acc[4] + acc[5]) + (acc[6] + acc[7]));
        }
        rss_s[tid] = res[0] + res[1];
    }
    __syncthreads();

    // ---- main: wave wv covers k in [wv*128, wv*128+128), 8 k per pass ----
    const float rss = rss_s[lane];
    const float* wc = cb + (size_t)c * KK * DD;
    const float* wssc = wss + (size_t)c * KK;
    unsigned long long best = 0xFFFFFFFFFFFFFFFFULL;

    for (int kg = 0; kg < 16; ++kg) {
        const int k0 = wv * 128 + kg * 8;
        float a[8];
        #pragma unroll
        for (int j = 0; j < 8; ++j) a[j] = 0.f;
        const float* w0 = wc + (size_t)k0 * DD;
        #pragma unroll 2
        for (int d = 0; d < DD; d += 4) {
            const float r0v = r_s[d + 0][lane];
            const float r1v = r_s[d + 1][lane];
            const float r2v = r_s[d + 2][lane];
            const float r3v = r_s[d + 3][lane];
            #pragma unroll
            for (int j = 0; j < 8; ++j) {
                const float4 w4 = *(const float4*)(w0 + (size_t)j * DD + d);
                a[j] = __builtin_fmaf(r0v, w4.x, a[j]);
                a[j] = __builtin_fmaf(r1v, w4.y, a[j]);
                a[j] = __builtin_fmaf(r2v, w4.z, a[j]);
                a[j] = __builtin_fmaf(r3v, w4.w, a[j]);
            }
        }
        #pragma unroll
        for (int j = 0; j < 8; ++j) {
            const float sc = (rss - 2.0f * a[j]) + wssc[k0 + j];
            unsigned u = __float_as_uint(sc);
            u = ((int)u < 0) ? ~u : (u | 0x80000000u);
            const unsigned long long e = ((unsigned long long)u << 32) | (unsigned)(k0 + j);
            if (e < best) best = e;
        }
    }
    arena[wv][lane] = best;
    __syncthreads();
    if (tid < 64) {
        unsigned long long m = arena[0][tid];
        #pragma unroll
        for (int w = 1; w < 8; ++w) {
            const unsigned long long x = arena[w][tid];
            if (x < m) m = x;
        }
        out_idx[(size_t)(row0 + tid) * NCB + c] = (float)(int)(m & 0xFFFFFFFFULL);
    }
}

// ---- quantized (fp32 sequential accumulation, reference order) + last loss ----
__global__ void final_kernel(const float* __restrict__ z, const float* __restrict__ cb,
                             const float* __restrict__ out_idx, float* __restrict__ outq,
                             double* __restrict__ loss)
{
    const int lane = threadIdx.x & 63;
    const int wid = (blockIdx.x * blockDim.x + threadIdx.x) >> 6;
    if (wid >= NROWS) return;
    const int n = wid, d = lane * 4;
    float4 rv = *(const float4*)(z + (size_t)n * DD + d);
    float q0 = 0.f, q1 = 0.f, q2 = 0.f, q3 = 0.f;
    for (int j = 0; j < NCB; ++j) {
        const int hidx = (int)out_idx[(size_t)n * NCB + j];
        const float4 wv = *(const float4*)(cb + ((size_t)j * KK + hidx) * DD + d);
        q0 += wv.x; q1 += wv.y; q2 += wv.z; q3 += wv.w;
        rv.x -= wv.x; rv.y -= wv.y; rv.z -= wv.z; rv.w -= wv.w;
    }
    *(float4*)(outq + (size_t)n * DD + d) = make_float4(q0, q1, q2, q3);
    double ss = (double)rv.x * rv.x + (double)rv.y * rv.y +
                (double)rv.z * rv.z + (double)rv.w * rv.w;
    for (int off = 32; off; off >>= 1) ss += __shfl_down(ss, off);
    if (lane == 0) atomicAdd(&loss[NCB - 1], ss);
}

__global__ void loss_write_kernel(const double* __restrict__ loss, float* __restrict__ out_loss) {
    double s = 0.0;
    for (int i = 0; i < NCB; ++i) s += loss[i];
    *out_loss = (float)(s / 16777216.0);
}

extern "C" void kernel_launch(void* const* d_in, const int* in_sizes, int n_in,
                              void* d_out, int out_size, void* d_ws, size_t ws_size,
                              hipStream_t stream)
{
    const float* z  = (const float*)d_in[0];
    const float* cb = (const float*)d_in[1];
    float* outq     = (float*)d_out;
    float* out_idx  = outq + QN;
    float* out_loss = outq + QN + IDXN;

    double* loss = (double*)d_ws;                 // 64 B
    float*  wss  = (float*)((char*)d_ws + 64);    // 32 KB

    hipMemsetAsync(d_ws, 0, 64, stream);
    wss_kernel<<<dim3((NCB * KK + 255) / 256), dim3(256), 0, stream>>>(cb, wss);
    for (int c = 0; c < NCB; ++c) {
        step_kernel<<<dim3(NROWS / 64), dim3(512), 0, stream>>>(z, cb, out_idx, wss, loss, c);
    }
    final_kernel<<<dim3(NROWS / 4), dim3(256), 0, stream>>>(z, cb, out_idx, outq, loss);
    loss_write_kernel<<<1, 1, 0, stream>>>(loss, out_loss);
}

// Round 5
// 9711.960 us; speedup vs baseline: 23.3383x; 1.6415x over previous
//
#include <hip/hip_runtime.h>

#define NROWS 65536
#define DD 256
#define KK 1024
#define NCB 8
#define QN 16777216
#define IDXN 524288

#define ROWS 64      // rows per block
#define KT 64        // k per LDS tile
#define NTILES (KK/KT)

// Defeat -ffp-contract=fast where a separately-rounded product is required.
__device__ __forceinline__ float fp32_barrier(float x) {
    asm volatile("" : "+v"(x));
    return x;
}

// ---- numpy pairwise ||w||^2 per codeword (bitwise np.sum semantics) ----
__global__ void wss_kernel(const float* __restrict__ cb, float* __restrict__ wss) {
    const int g = blockIdx.x * blockDim.x + threadIdx.x;
    if (g >= NCB * KK) return;
    const float* w = cb + (size_t)g * DD;
    float res0 = 0.f, res1 = 0.f;
    #pragma unroll
    for (int half = 0; half < 2; ++half) {
        const float* p = w + half * 128;
        float acc[8];
        #pragma unroll
        for (int j = 0; j < 8; ++j) acc[j] = fp32_barrier(p[j] * p[j]);
        #pragma unroll
        for (int i = 8; i < 128; i += 8)
            #pragma unroll
            for (int j = 0; j < 8; ++j) acc[j] += fp32_barrier(p[i + j] * p[i + j]);
        const float t = ((acc[0] + acc[1]) + (acc[2] + acc[3])) +
                        ((acc[4] + acc[5]) + (acc[6] + acc[7]));
        if (half == 0) res0 = t; else res1 = t;
    }
    wss[g] = res0 + res1;
}

// ---- one RVQ step: k-major waves, W tiled through LDS ----
// Bitwise-identical arithmetic to R3/R4: each (row,k) accumulator is one fp32
// fma chain over d=0..255 ascending; score = (rss - 2*a) + wss with numpy-
// pairwise rss/wss; first-min argmin (k packed in low bits of the encoding).
__launch_bounds__(512, 1)
__global__ void step_kernel(const float* __restrict__ z, const float* __restrict__ cb,
                            float* __restrict__ out_idx, const float* __restrict__ wss,
                            double* __restrict__ loss, int c)
{
    __shared__ float r_s[ROWS][260];   // 66.6 KB, pad 260: 8-way balanced banks
    __shared__ float W_s[KT][260];     // 66.6 KB
    __shared__ float rss_s[ROWS];
    __shared__ double lred[8];

    const int tid = threadIdx.x;
    const int lane = tid & 63;
    const int wv = tid >> 6;
    const int row0 = blockIdx.x * ROWS;
    const size_t cK = (size_t)c * KK;
    const float* Wc = cb + cK * DD;

    // ---- stage residual tile: fp32 reference trajectory (elementwise subs) ----
    {
        const int row = tid >> 3;           // 0..63
        const int d0 = (tid & 7) * 32;      // 8 chunks of 32 d
        const int n = row0 + row;
        float rr[32];
        const float* zr = z + (size_t)n * DD + d0;
        #pragma unroll
        for (int q = 0; q < 8; ++q) {
            const float4 v = *(const float4*)(zr + q * 4);
            rr[q * 4 + 0] = v.x; rr[q * 4 + 1] = v.y;
            rr[q * 4 + 2] = v.z; rr[q * 4 + 3] = v.w;
        }
        for (int h = 0; h < c; ++h) {
            const int ih = (int)out_idx[(size_t)n * NCB + h];
            const float* w = cb + ((size_t)h * KK + ih) * DD + d0;
            #pragma unroll
            for (int q = 0; q < 8; ++q) {
                const float4 v = *(const float4*)(w + q * 4);
                rr[q * 4 + 0] -= v.x; rr[q * 4 + 1] -= v.y;
                rr[q * 4 + 2] -= v.z; rr[q * 4 + 3] -= v.w;
            }
        }
        double ssq = 0.0;
        #pragma unroll
        for (int q = 0; q < 8; ++q) {
            *(float4*)&r_s[row][d0 + q * 4] = make_float4(rr[q*4], rr[q*4+1], rr[q*4+2], rr[q*4+3]);
            #pragma unroll
            for (int j = 0; j < 4; ++j) {
                const double v = (double)rr[q * 4 + j];
                ssq += v * v;
            }
        }
        if (c > 0) {
            for (int off = 32; off; off >>= 1) ssq += __shfl_down(ssq, off);
            if (lane == 0) lred[wv] = ssq;
        }
    }
    __syncthreads();
    if (c > 0 && tid == 0) {
        double s = 0.0;
        #pragma unroll
        for (int w = 0; w < 8; ++w) s += lred[w];
        atomicAdd(&loss[c - 1], s);
    }

    // ---- rss: numpy pairwise (pw128 + pw128), one row per lane of wave 0 ----
    if (tid < 64) {
        float res[2];
        #pragma unroll
        for (int half = 0; half < 2; ++half) {
            const int base = half * 128;
            float acc[8];
            #pragma unroll
            for (int j = 0; j < 8; ++j) {
                const float x = r_s[tid][base + j];
                acc[j] = fp32_barrier(x * x);
            }
            #pragma unroll
            for (int i = 8; i < 128; i += 8)
                #pragma unroll
                for (int j = 0; j < 8; ++j) {
                    const float x = r_s[tid][base + i + j];
                    acc[j] += fp32_barrier(x * x);
                }
            res[half] = ((acc[0] + acc[1]) + (acc[2] + acc[3])) +
                        ((acc[4] + acc[5]) + (acc[6] + acc[7]));
        }
        rss_s[tid] = res[0] + res[1];
    }

    // ---- prologue: load W tile 0 (flat-coalesced), write to LDS ----
    float4 pre[8];
    #pragma unroll
    for (int q = 0; q < 8; ++q) {
        const int f = tid + 512 * q;            // float4 index within 64KB tile
        pre[q] = *(const float4*)(Wc + 4 * (size_t)f);
    }
    __syncthreads();   // also covers rss_s
    #pragma unroll
    for (int q = 0; q < 8; ++q) {
        const int f = tid + 512 * q;
        const int k = f >> 6, d = (f & 63) * 4;
        *(float4*)&W_s[k][d] = pre[q];
    }
    __syncthreads();

    unsigned long long best[8];
    #pragma unroll
    for (int rr = 0; rr < 8; ++rr) best[rr] = 0xFFFFFFFFFFFFFFFFULL;

    const int myrow0 = wv * 8;
    float rssv[8];
    #pragma unroll
    for (int rr = 0; rr < 8; ++rr) rssv[rr] = rss_s[myrow0 + rr];

    for (int t = 0; t < NTILES; ++t) {
        // issue next tile's global loads early; consumed after this compute
        if (t + 1 < NTILES) {
            const float* Wn = Wc + (size_t)(t + 1) * KT * DD;
            #pragma unroll
            for (int q = 0; q < 8; ++q) {
                const int f = tid + 512 * q;
                pre[q] = *(const float4*)(Wn + 4 * (size_t)f);
            }
        }

        const int myk = t * KT + lane;
        const float mywss = wss[cK + myk];
        float a[8];
        #pragma unroll
        for (int rr = 0; rr < 8; ++rr) a[rr] = 0.f;

        for (int d = 0; d < DD; d += 8) {
            const float4 w0 = *(const float4*)&W_s[lane][d];
            const float4 w1 = *(const float4*)&W_s[lane][d + 4];
            #pragma unroll
            for (int rr = 0; rr < 8; ++rr) {
                const float4 ra = *(const float4*)&r_s[myrow0 + rr][d];
                const float4 rb = *(const float4*)&r_s[myrow0 + rr][d + 4];
                float acc = a[rr];
                acc = __builtin_fmaf(ra.x, w0.x, acc);
                acc = __builtin_fmaf(ra.y, w0.y, acc);
                acc = __builtin_fmaf(ra.z, w0.z, acc);
                acc = __builtin_fmaf(ra.w, w0.w, acc);
                acc = __builtin_fmaf(rb.x, w1.x, acc);
                acc = __builtin_fmaf(rb.y, w1.y, acc);
                acc = __builtin_fmaf(rb.z, w1.z, acc);
                acc = __builtin_fmaf(rb.w, w1.w, acc);
                a[rr] = acc;
            }
        }

        #pragma unroll
        for (int rr = 0; rr < 8; ++rr) {
            const float sc = (rssv[rr] - 2.0f * a[rr]) + mywss;
            unsigned u = __float_as_uint(sc);
            u = ((int)u < 0) ? ~u : (u | 0x80000000u);
            const unsigned long long e = ((unsigned long long)u << 32) | (unsigned)myk;
            if (e < best[rr]) best[rr] = e;
        }

        __syncthreads();   // everyone done reading W_s
        if (t + 1 < NTILES) {
            #pragma unroll
            for (int q = 0; q < 8; ++q) {
                const int f = tid + 512 * q;
                const int k = f >> 6, d = (f & 63) * 4;
                *(float4*)&W_s[k][d] = pre[q];
            }
        }
        __syncthreads();
    }

    // ---- per-row argmin across the wave's 64 lanes (k in low bits) ----
    #pragma unroll
    for (int rr = 0; rr < 8; ++rr) {
        unsigned long long m = best[rr];
        #pragma unroll
        for (int off = 1; off < 64; off <<= 1) {
            const unsigned long long o = __shfl_xor(m, off);
            if (o < m) m = o;
        }
        if (lane == 0)
            out_idx[(size_t)(row0 + myrow0 + rr) * NCB + c] = (float)(int)(m & 0xFFFFFFFFULL);
    }
}

// ---- quantized (fp32 sequential accumulation, reference order) + last loss ----
__global__ void final_kernel(const float* __restrict__ z, const float* __restrict__ cb,
                             const float* __restrict__ out_idx, float* __restrict__ outq,
                             double* __restrict__ loss)
{
    const int lane = threadIdx.x & 63;
    const int wid = (blockIdx.x * blockDim.x + threadIdx.x) >> 6;
    if (wid >= NROWS) return;
    const int n = wid, d = lane * 4;
    float4 rv = *(const float4*)(z + (size_t)n * DD + d);
    float q0 = 0.f, q1 = 0.f, q2 = 0.f, q3 = 0.f;
    for (int j = 0; j < NCB; ++j) {
        const int hidx = (int)out_idx[(size_t)n * NCB + j];
        const float4 wv = *(const float4*)(cb + ((size_t)j * KK + hidx) * DD + d);
        q0 += wv.x; q1 += wv.y; q2 += wv.z; q3 += wv.w;
        rv.x -= wv.x; rv.y -= wv.y; rv.z -= wv.z; rv.w -= wv.w;
    }
    *(float4*)(outq + (size_t)n * DD + d) = make_float4(q0, q1, q2, q3);
    double ss = (double)rv.x * rv.x + (double)rv.y * rv.y +
                (double)rv.z * rv.z + (double)rv.w * rv.w;
    for (int off = 32; off; off >>= 1) ss += __shfl_down(ss, off);
    if (lane == 0) atomicAdd(&loss[NCB - 1], ss);
}

__global__ void loss_write_kernel(const double* __restrict__ loss, float* __restrict__ out_loss) {
    double s = 0.0;
    for (int i = 0; i < NCB; ++i) s += loss[i];
    *out_loss = (float)(s / 16777216.0);
}

extern "C" void kernel_launch(void* const* d_in, const int* in_sizes, int n_in,
                              void* d_out, int out_size, void* d_ws, size_t ws_size,
                              hipStream_t stream)
{
    const float* z  = (const float*)d_in[0];
    const float* cb = (const float*)d_in[1];
    float* outq     = (float*)d_out;
    float* out_idx  = outq + QN;
    float* out_loss = outq + QN + IDXN;

    double* loss = (double*)d_ws;                 // 64 B
    float*  wss  = (float*)((char*)d_ws + 64);    // 32 KB

    hipMemsetAsync(d_ws, 0, 64, stream);
    wss_kernel<<<dim3((NCB * KK + 255) / 256), dim3(256), 0, stream>>>(cb, wss);
    for (int c = 0; c < NCB; ++c) {
        step_kernel<<<dim3(NROWS / ROWS), dim3(512), 0, stream>>>(z, cb, out_idx, wss, loss, c);
    }
    final_kernel<<<dim3(NROWS / 4), dim3(256), 0, stream>>>(z, cb, out_idx, outq, loss);
    loss_write_kernel<<<1, 1, 0, stream>>>(loss, out_loss);
}

// Round 6
// 5520.134 us; speedup vs baseline: 41.0607x; 1.7594x over previous
//
#include <hip/hip_runtime.h>

#define NROWS 65536
#define DD 256
#define KK 1024
#define NCB 8
#define QN 16777216
#define IDXN 524288

#define ROWS 64          // rows per block
#define CH 16            // d per W-chunk
#define NCHUNK (DD/CH)   // 16
#define WRL 17           // W_s row length (pad: odd => bank permutation)

// Defeat -ffp-contract=fast where a separately-rounded product is required.
__device__ __forceinline__ float fp32_barrier(float x) {
    asm volatile("" : "+v"(x));
    return x;
}

// ---- numpy pairwise ||w||^2 per codeword (bitwise np.sum semantics) ----
__global__ void wss_kernel(const float* __restrict__ cb, float* __restrict__ wss) {
    const int g = blockIdx.x * blockDim.x + threadIdx.x;
    if (g >= NCB * KK) return;
    const float* w = cb + (size_t)g * DD;
    float res0 = 0.f, res1 = 0.f;
    #pragma unroll
    for (int half = 0; half < 2; ++half) {
        const float* p = w + half * 128;
        float acc[8];
        #pragma unroll
        for (int j = 0; j < 8; ++j) acc[j] = fp32_barrier(p[j] * p[j]);
        #pragma unroll
        for (int i = 8; i < 128; i += 8)
            #pragma unroll
            for (int j = 0; j < 8; ++j) acc[j] += fp32_barrier(p[i + j] * p[i + j]);
        const float t = ((acc[0] + acc[1]) + (acc[2] + acc[3])) +
                        ((acc[4] + acc[5]) + (acc[6] + acc[7]));
        if (half == 0) res0 = t; else res1 = t;
    }
    wss[g] = res0 + res1;
}

// ---- one RVQ step: 16x8 register tile per lane, W chunked through LDS ----
// Bitwise-identical arithmetic to R3-R5: each (row,k) accumulator is one fp32
// fma chain over d=0..255 ascending (accumulator persists across d-chunks);
// score = (rss - 2*a) + wss with numpy-pairwise rss/wss; first-min argmin.
__launch_bounds__(512, 2)
__global__ void step_kernel(const float* __restrict__ z, const float* __restrict__ cb,
                            float* __restrict__ out_idx, const float* __restrict__ wss,
                            double* __restrict__ loss, int c)
{
    __shared__ float r_s[ROWS][260];           // 66.6 KB
    __shared__ float W_s[KK * WRL];            // 69.6 KB, [k][0..15] chunk slice
    __shared__ float rss_s[ROWS];
    __shared__ unsigned long long arena[ROWS][2];
    __shared__ double lred[8];

    const int tid = threadIdx.x;
    const int lane = tid & 63;
    const int wv = tid >> 6;
    const int rowbase = (wv & 3) * 16;         // this wave's 16 rows
    const int khalf = wv >> 2;                 // this wave's 512-k half
    const int row0 = blockIdx.x * ROWS;
    const size_t cK = (size_t)c * KK;
    const float* Wc = cb + cK * DD;

    // ---- stage residual tile: fp32 reference trajectory (elementwise subs) ----
    {
        const int row = tid >> 3;              // 0..63
        const int d0 = (tid & 7) * 32;         // 8 chunks of 32 d
        const int n = row0 + row;
        float rr[32];
        const float* zr = z + (size_t)n * DD + d0;
        #pragma unroll
        for (int q = 0; q < 8; ++q) {
            const float4 v = *(const float4*)(zr + q * 4);
            rr[q * 4 + 0] = v.x; rr[q * 4 + 1] = v.y;
            rr[q * 4 + 2] = v.z; rr[q * 4 + 3] = v.w;
        }
        for (int h = 0; h < c; ++h) {
            const int ih = (int)out_idx[(size_t)n * NCB + h];
            const float* w = cb + ((size_t)h * KK + ih) * DD + d0;
            #pragma unroll
            for (int q = 0; q < 8; ++q) {
                const float4 v = *(const float4*)(w + q * 4);
                rr[q * 4 + 0] -= v.x; rr[q * 4 + 1] -= v.y;
                rr[q * 4 + 2] -= v.z; rr[q * 4 + 3] -= v.w;
            }
        }
        double ssq = 0.0;
        #pragma unroll
        for (int q = 0; q < 8; ++q) {
            *(float4*)&r_s[row][d0 + q * 4] =
                make_float4(rr[q*4], rr[q*4+1], rr[q*4+2], rr[q*4+3]);
            #pragma unroll
            for (int j = 0; j < 4; ++j) {
                const double v = (double)rr[q * 4 + j];
                ssq += v * v;
            }
        }
        if (c > 0) {
            for (int off = 32; off; off >>= 1) ssq += __shfl_down(ssq, off);
            if (lane == 0) lred[wv] = ssq;
        }
    }
    __syncthreads();
    if (c > 0 && tid == 0) {
        double s = 0.0;
        #pragma unroll
        for (int w = 0; w < 8; ++w) s += lred[w];
        atomicAdd(&loss[c - 1], s);
    }

    // ---- rss: numpy pairwise (pw128 + pw128), one row per lane of wave 0 ----
    if (tid < 64) {
        float res[2];
        #pragma unroll
        for (int half = 0; half < 2; ++half) {
            const int base = half * 128;
            float acc[8];
            #pragma unroll
            for (int j = 0; j < 8; ++j) {
                const float x = r_s[tid][base + j];
                acc[j] = fp32_barrier(x * x);
            }
            #pragma unroll
            for (int i = 8; i < 128; i += 8)
                #pragma unroll
                for (int j = 0; j < 8; ++j) {
                    const float x = r_s[tid][base + i + j];
                    acc[j] += fp32_barrier(x * x);
                }
            res[half] = ((acc[0] + acc[1]) + (acc[2] + acc[3])) +
                        ((acc[4] + acc[5]) + (acc[6] + acc[7]));
        }
        rss_s[tid] = res[0] + res[1];
    }

    // ---- wss for my 8 k (k = khalf*512 + j*64 + lane) ----
    float wssv[8];
    #pragma unroll
    for (int j = 0; j < 8; ++j) wssv[j] = wss[cK + khalf * 512 + j * 64 + lane];

    float acc[16][8];
    #pragma unroll
    for (int rr = 0; rr < 16; ++rr)
        #pragma unroll
        for (int j = 0; j < 8; ++j) acc[rr][j] = 0.f;

    const int kbase_lane = (khalf * 512 + lane) * WRL;   // dwords into W_s

    #pragma unroll 1
    for (int ch = 0; ch < NCHUNK; ++ch) {
        __syncthreads();   // previous chunk's W_s readers done
        // stage W chunk: k = f>>2 (coalesced 64B runs), 4x b32 LDS writes
        {
            const float* src = Wc + ch * CH;
            #pragma unroll
            for (int q = 0; q < 8; ++q) {
                const int f = tid + 512 * q;
                const int k = f >> 2, quad = f & 3;
                const float4 v = *(const float4*)(src + (size_t)k * DD + quad * 4);
                float* dst = &W_s[k * WRL + quad * 4];
                dst[0] = v.x; dst[1] = v.y; dst[2] = v.z; dst[3] = v.w;
            }
        }
        __syncthreads();

        const int dbase = ch * CH;
        #pragma unroll
        for (int w2 = 0; w2 < CH / 2; ++w2) {
            const int dl = w2 * 2;
            float wv0[8], wv1[8];
            #pragma unroll
            for (int j = 0; j < 8; ++j) {
                wv0[j] = W_s[kbase_lane + j * 64 * WRL + dl];
                wv1[j] = W_s[kbase_lane + j * 64 * WRL + dl + 1];
            }
            float2 rv[16];
            #pragma unroll
            for (int rr = 0; rr < 16; ++rr)
                rv[rr] = *(const float2*)&r_s[rowbase + rr][dbase + dl];
            #pragma unroll
            for (int rr = 0; rr < 16; ++rr) {
                #pragma unroll
                for (int j = 0; j < 8; ++j) {
                    float a = acc[rr][j];
                    a = __builtin_fmaf(rv[rr].x, wv0[j], a);
                    a = __builtin_fmaf(rv[rr].y, wv1[j], a);
                    acc[rr][j] = a;
                }
            }
        }
    }

    // ---- scores + first-min argmin ----
    #pragma unroll
    for (int rr = 0; rr < 16; ++rr) {
        const float rs = rss_s[rowbase + rr];
        unsigned long long best = 0xFFFFFFFFFFFFFFFFULL;
        #pragma unroll
        for (int j = 0; j < 8; ++j) {
            const int kk = khalf * 512 + j * 64 + lane;
            const float sc = (rs - 2.0f * acc[rr][j]) + wssv[j];
            unsigned u = __float_as_uint(sc);
            u = ((int)u < 0) ? ~u : (u | 0x80000000u);
            const unsigned long long e = ((unsigned long long)u << 32) | (unsigned)kk;
            if (e < best) best = e;
        }
        #pragma unroll
        for (int off = 1; off < 64; off <<= 1) {
            const unsigned long long o = __shfl_xor(best, off);
            if (o < best) best = o;
        }
        if (lane == 0) arena[rowbase + rr][khalf] = best;
    }
    __syncthreads();
    if (tid < ROWS) {
        unsigned long long m = arena[tid][0];
        if (arena[tid][1] < m) m = arena[tid][1];
        out_idx[(size_t)(row0 + tid) * NCB + c] = (float)(int)(m & 0xFFFFFFFFULL);
    }
}

// ---- quantized (fp32 sequential accumulation, reference order) + last loss ----
__global__ void final_kernel(const float* __restrict__ z, const float* __restrict__ cb,
                             const float* __restrict__ out_idx, float* __restrict__ outq,
                             double* __restrict__ loss)
{
    const int lane = threadIdx.x & 63;
    const int wid = (blockIdx.x * blockDim.x + threadIdx.x) >> 6;
    if (wid >= NROWS) return;
    const int n = wid, d = lane * 4;
    float4 rv = *(const float4*)(z + (size_t)n * DD + d);
    float q0 = 0.f, q1 = 0.f, q2 = 0.f, q3 = 0.f;
    for (int j = 0; j < NCB; ++j) {
        const int hidx = (int)out_idx[(size_t)n * NCB + j];
        const float4 wv = *(const float4*)(cb + ((size_t)j * KK + hidx) * DD + d);
        q0 += wv.x; q1 += wv.y; q2 += wv.z; q3 += wv.w;
        rv.x -= wv.x; rv.y -= wv.y; rv.z -= wv.z; rv.w -= wv.w;
    }
    *(float4*)(outq + (size_t)n * DD + d) = make_float4(q0, q1, q2, q3);
    double ss = (double)rv.x * rv.x + (double)rv.y * rv.y +
                (double)rv.z * rv.z + (double)rv.w * rv.w;
    for (int off = 32; off; off >>= 1) ss += __shfl_down(ss, off);
    if (lane == 0) atomicAdd(&loss[NCB - 1], ss);
}

__global__ void loss_write_kernel(const double* __restrict__ loss, float* __restrict__ out_loss) {
    double s = 0.0;
    for (int i = 0; i < NCB; ++i) s += loss[i];
    *out_loss = (float)(s / 16777216.0);
}

extern "C" void kernel_launch(void* const* d_in, const int* in_sizes, int n_in,
                              void* d_out, int out_size, void* d_ws, size_t ws_size,
                              hipStream_t stream)
{
    const float* z  = (const float*)d_in[0];
    const float* cb = (const float*)d_in[1];
    float* outq     = (float*)d_out;
    float* out_idx  = outq + QN;
    float* out_loss = outq + QN + IDXN;

    double* loss = (double*)d_ws;                 // 64 B
    float*  wss  = (float*)((char*)d_ws + 64);    // 32 KB

    hipMemsetAsync(d_ws, 0, 64, stream);
    wss_kernel<<<dim3((NCB * KK + 255) / 256), dim3(256), 0, stream>>>(cb, wss);
    for (int c = 0; c < NCB; ++c) {
        step_kernel<<<dim3(NROWS / ROWS), dim3(512), 0, stream>>>(z, cb, out_idx, wss, loss, c);
    }
    final_kernel<<<dim3(NROWS / 4), dim3(256), 0, stream>>>(z, cb, out_idx, outq, loss);
    loss_write_kernel<<<1, 1, 0, stream>>>(loss, out_loss);
}